// Round 1
// baseline (704.167 us; speedup 1.0000x reference)
//
#include <hip/hip_runtime.h>
#include <hip/hip_bf16.h>
#include <stdint.h>

// Problem constants (AdaLoRALinear): out = x @ (W + 2*(P*Lambda*mask)@Q)^T
#define M_TOK 8192   // batch tokens
#define NF    4096   // OUT_F
#define KF    4096   // IN_F
#define RANK  64

typedef __attribute__((ext_vector_type(8))) short short8;   // 8 x bf16 (4 VGPRs)
typedef __attribute__((ext_vector_type(4))) float floatx4;  // MFMA acc

typedef const uint32_t __attribute__((address_space(1)))* gp1_t;
typedef uint32_t __attribute__((address_space(3)))* lp3_t;

__device__ __forceinline__ void load_lds16(const void* g, void* l) {
  // async global->LDS, 16 B per lane; LDS dest must be uniform_base + lane*16
  __builtin_amdgcn_global_load_lds((gp1_t)g, (lp3_t)l, 16, 0, 0);
}

// ---------------- Kernel 1: x (fp32) -> bf16, 8 elems/thread ----------------
__global__ void cast_f32_bf16(const float* __restrict__ in,
                              __hip_bfloat16* __restrict__ out) {
  size_t i = ((size_t)blockIdx.x * blockDim.x + threadIdx.x) * 8;
  float4 a = *(const float4*)(in + i);
  float4 b = *(const float4*)(in + i + 4);
  union { __hip_bfloat16 h[8]; uint4 u; } pk;
  pk.h[0] = __float2bfloat16(a.x);
  pk.h[1] = __float2bfloat16(a.y);
  pk.h[2] = __float2bfloat16(a.z);
  pk.h[3] = __float2bfloat16(a.w);
  pk.h[4] = __float2bfloat16(b.x);
  pk.h[5] = __float2bfloat16(b.y);
  pk.h[6] = __float2bfloat16(b.z);
  pk.h[7] = __float2bfloat16(b.w);
  *(uint4*)(out + i) = pk.u;
}

// ---- Kernel 2: W_eff[n][k] = W[n][k] + 2*sum_r P[n][r]*Lam[r]*mask[r]*Q[r][k],
//      cast to bf16. Tile 64n x 64k per block, 256 threads, rank staged in LDS.
__global__ __launch_bounds__(256) void build_weff(
    const float* __restrict__ W, const float* __restrict__ P,
    const float* __restrict__ Lam, const float* __restrict__ Q,
    const unsigned char* __restrict__ mask,   // jnp.bool_ -> 1 byte/elem
    __hip_bfloat16* __restrict__ Wb) {
  __shared__ float lam[RANK];
  __shared__ float plT[RANK][68];  // [r][n_local], padded vs bank conflicts
  __shared__ float Qs[RANK][68];   // [r][k_local]

  const int t = threadIdx.x;
  const int n0 = blockIdx.y * 64;
  const int k0 = blockIdx.x * 64;

  if (t < RANK) lam[t] = 2.0f * Lam[t] * (mask[t] ? 1.0f : 0.0f);
  __syncthreads();

  {
    // stage P^T * lam : thread t covers n_local = t&63, r-range (t>>6)*16..+15
    const int nl = t & 63;
    const int rg = (t >> 6) * 16;
    const float* p = P + (size_t)(n0 + nl) * RANK + rg;
#pragma unroll
    for (int j = 0; j < 16; j += 4) {
      float4 v = *(const float4*)(p + j);
      plT[rg + j + 0][nl] = v.x * lam[rg + j + 0];
      plT[rg + j + 1][nl] = v.y * lam[rg + j + 1];
      plT[rg + j + 2][nl] = v.z * lam[rg + j + 2];
      plT[rg + j + 3][nl] = v.w * lam[rg + j + 3];
    }
    // stage Q tile: thread t covers r = t>>2, k-range (t&3)*16..+15
    const int r = t >> 2;
    const int kc = (t & 3) * 16;
    const float* q = Q + (size_t)r * KF + k0 + kc;
#pragma unroll
    for (int j = 0; j < 16; j += 4) {
      float4 v = *(const float4*)(q + j);
      Qs[r][kc + j + 0] = v.x;
      Qs[r][kc + j + 1] = v.y;
      Qs[r][kc + j + 2] = v.z;
      Qs[r][kc + j + 3] = v.w;
    }
  }
  __syncthreads();

  const int tn4 = t >> 4;  // 0..15 -> n-group of 4
  const int tk4 = t & 15;  // 0..15 -> k-group of 4
  float accv[4][4];
#pragma unroll
  for (int i = 0; i < 4; i++) {
    float4 w = *(const float4*)(W + (size_t)(n0 + tn4 * 4 + i) * KF + k0 + tk4 * 4);
    accv[i][0] = w.x; accv[i][1] = w.y; accv[i][2] = w.z; accv[i][3] = w.w;
  }
#pragma unroll 8
  for (int r = 0; r < RANK; r++) {
    float4 p4 = *(const float4*)&plT[r][tn4 * 4];
    float4 q4 = *(const float4*)&Qs[r][tk4 * 4];
#define ROWFMA(i, pi)                                                  \
    accv[i][0] += (pi) * q4.x; accv[i][1] += (pi) * q4.y;              \
    accv[i][2] += (pi) * q4.z; accv[i][3] += (pi) * q4.w;
    ROWFMA(0, p4.x) ROWFMA(1, p4.y) ROWFMA(2, p4.z) ROWFMA(3, p4.w)
#undef ROWFMA
  }
#pragma unroll
  for (int i = 0; i < 4; i++) {
    union { __hip_bfloat16 h[4]; uint2 u; } pk;
    pk.h[0] = __float2bfloat16(accv[i][0]);
    pk.h[1] = __float2bfloat16(accv[i][1]);
    pk.h[2] = __float2bfloat16(accv[i][2]);
    pk.h[3] = __float2bfloat16(accv[i][3]);
    *(uint2*)(Wb + (size_t)(n0 + tn4 * 4 + i) * KF + k0 + tk4 * 4) = pk.u;
  }
}

// ---- Kernel 3: C[m][n] = sum_k A[m][k] * B[n][k]; A,B bf16 row-major, C fp32.
//      m97 structure: 128x128 tile, BK=32, global_load_lds width 16,
//      4 waves, each computing 64x64 via 4x4 grid of 16x16x32 bf16 MFMAs.
#define BM 128
#define BN 128
#define BK 32

__global__ __launch_bounds__(256) void gemm_xwt(
    const __hip_bfloat16* __restrict__ A,   // [M_TOK][KF]
    const __hip_bfloat16* __restrict__ B,   // [NF][KF]  (= W_eff, row = n)
    float* __restrict__ C) {                // [M_TOK][NF]
  __shared__ __hip_bfloat16 As[BM * BK];  // 8 KB, row-major [128][32]
  __shared__ __hip_bfloat16 Bs[BN * BK];  // 8 KB

  const int t = threadIdx.x;       // 0..255
  const int lane = t & 63;
  const int wave = t >> 6;         // 0..3
  const int wm = (wave & 1) * 64;  // wave sub-tile origin
  const int wn = (wave >> 1) * 64;
  const int bm = blockIdx.y;
  const int bn = blockIdx.x;

  const int frow = lane & 15;      // fragment row (m or n)
  const int kq = lane >> 4;        // k-quad: elements kq*8 .. kq*8+7

  floatx4 acc[4][4] = {};

  // staging: 512 chunks of 16 B per 128x32 tile; thread t takes chunks t, t+256.
  // chunk c -> row c>>2, col (c&3)*8. LDS byte offset = c*16 (lane-ordered).
  const __hip_bfloat16* Ap = A + (size_t)(bm * BM + (t >> 2)) * KF + (t & 3) * 8;
  const __hip_bfloat16* Bp = B + (size_t)(bn * BN + (t >> 2)) * KF + (t & 3) * 8;
  __hip_bfloat16* As0 = As + t * 8;
  __hip_bfloat16* Bs0 = Bs + t * 8;

  for (int k0 = 0; k0 < KF; k0 += BK) {
    load_lds16(Ap, As0);
    load_lds16(Ap + (size_t)64 * KF, As0 + 64 * BK);
    load_lds16(Bp, Bs0);
    load_lds16(Bp + (size_t)64 * KF, Bs0 + 64 * BK);
    Ap += BK;
    Bp += BK;
    __syncthreads();  // emits s_waitcnt vmcnt(0) before s_barrier -> LDS valid

    short8 af[4], bf[4];
#pragma unroll
    for (int i = 0; i < 4; i++) {
      af[i] = *(const short8*)(As + (wm + i * 16 + frow) * BK + kq * 8);
      bf[i] = *(const short8*)(Bs + (wn + i * 16 + frow) * BK + kq * 8);
    }
#pragma unroll
    for (int i = 0; i < 4; i++)
#pragma unroll
      for (int j = 0; j < 4; j++)
        acc[i][j] = __builtin_amdgcn_mfma_f32_16x16x32_bf16(af[i], bf[j], acc[i][j], 0, 0, 0);
    __syncthreads();
  }

  // epilogue: D mapping col(n)=lane&15, row(m)=(lane>>4)*4+reg  [m89-verified]
  const int col0 = bn * BN + wn + (lane & 15);
  const int row0 = bm * BM + wm + (lane >> 4) * 4;
#pragma unroll
  for (int i = 0; i < 4; i++)
#pragma unroll
    for (int j = 0; j < 4; j++)
#pragma unroll
      for (int r = 0; r < 4; r++)
        C[(size_t)(row0 + i * 16 + r) * NF + (col0 + j * 16)] = acc[i][j][r];
}

extern "C" void kernel_launch(void* const* d_in, const int* in_sizes, int n_in,
                              void* d_out, int out_size, void* d_ws, size_t ws_size,
                              hipStream_t stream) {
  const float* x      = (const float*)d_in[0];  // [8192][4096]
  const float* weight = (const float*)d_in[1];  // [4096][4096]
  const float* P      = (const float*)d_in[2];  // [4096][64]
  const float* Lam    = (const float*)d_in[3];  // [64]
  const float* Q      = (const float*)d_in[4];  // [64][4096]
  const unsigned char* mask = (const unsigned char*)d_in[5];  // [64] bool8
  float* out = (float*)d_out;

  __hip_bfloat16* Xb = (__hip_bfloat16*)d_ws;                         // 64 MB
  __hip_bfloat16* Wb = (__hip_bfloat16*)((char*)d_ws + (size_t)M_TOK * KF * 2);  // 32 MB

  // 1) x -> bf16
  cast_f32_bf16<<<(M_TOK * KF) / (256 * 8), 256, 0, stream>>>(x, Xb);
  // 2) W_eff -> bf16
  build_weff<<<dim3(KF / 64, NF / 64), 256, 0, stream>>>(weight, P, Lam, Q, mask, Wb);
  // 3) out = Xb @ Wb^T
  gemm_xwt<<<dim3(NF / BN, M_TOK / BM), 256, 0, stream>>>(Xb, Wb, out);
}

// Round 2
// 691.456 us; speedup vs baseline: 1.0184x; 1.0184x over previous
//
#include <hip/hip_runtime.h>
#include <hip/hip_bf16.h>
#include <stdint.h>

// Problem constants (AdaLoRALinear): out = x @ (W + 2*(P*Lambda*mask)@Q)^T
#define M_TOK 8192   // batch tokens
#define NF    4096   // OUT_F
#define KF    4096   // IN_F
#define RANK  64

typedef __attribute__((ext_vector_type(8))) short short8;   // 8 x bf16 (4 VGPRs)
typedef __attribute__((ext_vector_type(4))) float floatx4;  // MFMA acc

typedef const uint32_t __attribute__((address_space(1)))* gp1_t;
typedef uint32_t __attribute__((address_space(3)))* lp3_t;

__device__ __forceinline__ void load_lds16(const void* g, void* l) {
  // async global->LDS, 16 B per lane; LDS dest must be uniform_base + lane*16
  __builtin_amdgcn_global_load_lds((gp1_t)g, (lp3_t)l, 16, 0, 0);
}

// ---------------- Kernel 1: x (fp32) -> bf16, 8 elems/thread ----------------
__global__ void cast_f32_bf16(const float* __restrict__ in,
                              __hip_bfloat16* __restrict__ out) {
  size_t i = ((size_t)blockIdx.x * blockDim.x + threadIdx.x) * 8;
  float4 a = *(const float4*)(in + i);
  float4 b = *(const float4*)(in + i + 4);
  union { __hip_bfloat16 h[8]; uint4 u; } pk;
  pk.h[0] = __float2bfloat16(a.x);
  pk.h[1] = __float2bfloat16(a.y);
  pk.h[2] = __float2bfloat16(a.z);
  pk.h[3] = __float2bfloat16(a.w);
  pk.h[4] = __float2bfloat16(b.x);
  pk.h[5] = __float2bfloat16(b.y);
  pk.h[6] = __float2bfloat16(b.z);
  pk.h[7] = __float2bfloat16(b.w);
  *(uint4*)(out + i) = pk.u;
}

// ---- Kernel 2: W_eff[n][k] = W[n][k] + 2*sum_r P[n][r]*Lam[r]*mask[r]*Q[r][k],
//      cast to bf16. Tile 64n x 64k per block, 256 threads, rank staged in LDS.
__global__ __launch_bounds__(256) void build_weff(
    const float* __restrict__ W, const float* __restrict__ P,
    const float* __restrict__ Lam, const float* __restrict__ Q,
    const unsigned char* __restrict__ mask,   // jnp.bool_ -> 1 byte/elem
    __hip_bfloat16* __restrict__ Wb) {
  __shared__ float lam[RANK];
  __shared__ float plT[RANK][68];  // [r][n_local], padded vs bank conflicts
  __shared__ float Qs[RANK][68];   // [r][k_local]

  const int t = threadIdx.x;
  const int n0 = blockIdx.y * 64;
  const int k0 = blockIdx.x * 64;

  if (t < RANK) lam[t] = 2.0f * Lam[t] * (mask[t] ? 1.0f : 0.0f);
  __syncthreads();

  {
    // stage P^T * lam : thread t covers n_local = t&63, r-range (t>>6)*16..+15
    const int nl = t & 63;
    const int rg = (t >> 6) * 16;
    const float* p = P + (size_t)(n0 + nl) * RANK + rg;
#pragma unroll
    for (int j = 0; j < 16; j += 4) {
      float4 v = *(const float4*)(p + j);
      plT[rg + j + 0][nl] = v.x * lam[rg + j + 0];
      plT[rg + j + 1][nl] = v.y * lam[rg + j + 1];
      plT[rg + j + 2][nl] = v.z * lam[rg + j + 2];
      plT[rg + j + 3][nl] = v.w * lam[rg + j + 3];
    }
    // stage Q tile: thread t covers r = t>>2, k-range (t&3)*16..+15
    const int r = t >> 2;
    const int kc = (t & 3) * 16;
    const float* q = Q + (size_t)r * KF + k0 + kc;
#pragma unroll
    for (int j = 0; j < 16; j += 4) {
      float4 v = *(const float4*)(q + j);
      Qs[r][kc + j + 0] = v.x;
      Qs[r][kc + j + 1] = v.y;
      Qs[r][kc + j + 2] = v.z;
      Qs[r][kc + j + 3] = v.w;
    }
  }
  __syncthreads();

  const int tn4 = t >> 4;  // 0..15 -> n-group of 4
  const int tk4 = t & 15;  // 0..15 -> k-group of 4
  float accv[4][4];
#pragma unroll
  for (int i = 0; i < 4; i++) {
    float4 w = *(const float4*)(W + (size_t)(n0 + tn4 * 4 + i) * KF + k0 + tk4 * 4);
    accv[i][0] = w.x; accv[i][1] = w.y; accv[i][2] = w.z; accv[i][3] = w.w;
  }
#pragma unroll 8
  for (int r = 0; r < RANK; r++) {
    float4 p4 = *(const float4*)&plT[r][tn4 * 4];
    float4 q4 = *(const float4*)&Qs[r][tk4 * 4];
#define ROWFMA(i, pi)                                                  \
    accv[i][0] += (pi) * q4.x; accv[i][1] += (pi) * q4.y;              \
    accv[i][2] += (pi) * q4.z; accv[i][3] += (pi) * q4.w;
    ROWFMA(0, p4.x) ROWFMA(1, p4.y) ROWFMA(2, p4.z) ROWFMA(3, p4.w)
#undef ROWFMA
  }
#pragma unroll
  for (int i = 0; i < 4; i++) {
    union { __hip_bfloat16 h[4]; uint2 u; } pk;
    pk.h[0] = __float2bfloat16(accv[i][0]);
    pk.h[1] = __float2bfloat16(accv[i][1]);
    pk.h[2] = __float2bfloat16(accv[i][2]);
    pk.h[3] = __float2bfloat16(accv[i][3]);
    *(uint2*)(Wb + (size_t)(n0 + tn4 * 4 + i) * KF + k0 + tk4 * 4) = pk.u;
  }
}

// ---- Kernel 3: C[m][n] = sum_k A[m][k] * B[n][k]; A,B bf16 row-major, C fp32.
//      m97 structure: 128x128 tile, BK=32, global_load_lds width 16,
//      4 waves, each computing 64x64 via 4x4 grid of 16x16x32 bf16 MFMAs.
//
// LDS swizzle (kills the 8-way bank conflict of the naive 64B-row layout):
//   chunk (row r, 16B-col c in 0..3) lives at LDS offset r*64 + ((c+(r>>1))&3)*16.
//   Writer thread t (forced LDS dst = t*16 by global_load_lds) therefore
//   fetches global col ((t&3)-((t>>3)&3))&3 of row t>>2.
//   Reader lane (frow,kq) reads elem offset ((kq+(frow>>1))&3)*8 of its row.
//   Bank slots over a wave64 b128 read: (frow&1)*16 + ((kq+(frow>>1))&3)*4
//   -> all 8 slots x 8 lanes each = uniform = conflict-free.
#define BM 128
#define BN 128
#define BK 32

__global__ __launch_bounds__(256) void gemm_xwt(
    const __hip_bfloat16* __restrict__ A,   // [M_TOK][KF]
    const __hip_bfloat16* __restrict__ B,   // [NF][KF]  (= W_eff, row = n)
    float* __restrict__ C) {                // [M_TOK][NF]
  __shared__ __hip_bfloat16 As[BM * BK];  // 8 KB, swizzled layout (see above)
  __shared__ __hip_bfloat16 Bs[BN * BK];  // 8 KB

  const int t = threadIdx.x;       // 0..255
  const int lane = t & 63;
  const int wave = t >> 6;         // 0..3
  const int wm = (wave & 1) * 64;  // wave sub-tile origin
  const int wn = (wave >> 1) * 64;
  const int bm = blockIdx.y;
  const int bn = blockIdx.x;

  const int frow = lane & 15;      // fragment row (m or n)
  const int kq = lane >> 4;        // k-quad: elements kq*8 .. kq*8+7
  const int swz = ((kq + (frow >> 1)) & 3) * 8;  // swizzled k-elem offset

  floatx4 acc[4][4] = {};

  // staging: thread t fills LDS bytes t*16 (rows 0..63) and 4096+t*16
  // (rows 64..127). Source col is the swizzle-inverse of slot t&3.
  const int sr = t >> 2;                              // LDS row (first half)
  const int sc = ((t & 3) - ((t >> 3) & 3)) & 3;      // global 16B col
  const __hip_bfloat16* Ap = A + (size_t)(bm * BM + sr) * KF + sc * 8;
  const __hip_bfloat16* Bp = B + (size_t)(bn * BN + sr) * KF + sc * 8;
  __hip_bfloat16* As0 = As + t * 8;
  __hip_bfloat16* Bs0 = Bs + t * 8;

  for (int k0 = 0; k0 < KF; k0 += BK) {
    load_lds16(Ap, As0);
    load_lds16(Ap + (size_t)64 * KF, As0 + 64 * BK);
    load_lds16(Bp, Bs0);
    load_lds16(Bp + (size_t)64 * KF, Bs0 + 64 * BK);
    Ap += BK;
    Bp += BK;
    __syncthreads();  // emits s_waitcnt vmcnt(0) before s_barrier -> LDS valid

    short8 af[4], bf[4];
#pragma unroll
    for (int i = 0; i < 4; i++) {
      af[i] = *(const short8*)(As + (wm + i * 16 + frow) * BK + swz);
      bf[i] = *(const short8*)(Bs + (wn + i * 16 + frow) * BK + swz);
    }
#pragma unroll
    for (int i = 0; i < 4; i++)
#pragma unroll
      for (int j = 0; j < 4; j++)
        acc[i][j] = __builtin_amdgcn_mfma_f32_16x16x32_bf16(af[i], bf[j], acc[i][j], 0, 0, 0);
    __syncthreads();
  }

  // epilogue: D mapping col(n)=lane&15, row(m)=(lane>>4)*4+reg  [m89-verified]
  const int col0 = bn * BN + wn + (lane & 15);
  const int row0 = bm * BM + wm + (lane >> 4) * 4;
#pragma unroll
  for (int i = 0; i < 4; i++)
#pragma unroll
    for (int j = 0; j < 4; j++)
#pragma unroll
      for (int r = 0; r < 4; r++)
        C[(size_t)(row0 + i * 16 + r) * NF + (col0 + j * 16)] = acc[i][j][r];
}

extern "C" void kernel_launch(void* const* d_in, const int* in_sizes, int n_in,
                              void* d_out, int out_size, void* d_ws, size_t ws_size,
                              hipStream_t stream) {
  const float* x      = (const float*)d_in[0];  // [8192][4096]
  const float* weight = (const float*)d_in[1];  // [4096][4096]
  const float* P      = (const float*)d_in[2];  // [4096][64]
  const float* Lam    = (const float*)d_in[3];  // [64]
  const float* Q      = (const float*)d_in[4];  // [64][4096]
  const unsigned char* mask = (const unsigned char*)d_in[5];  // [64] bool8
  float* out = (float*)d_out;

  __hip_bfloat16* Xb = (__hip_bfloat16*)d_ws;                         // 64 MB
  __hip_bfloat16* Wb = (__hip_bfloat16*)((char*)d_ws + (size_t)M_TOK * KF * 2);  // 32 MB

  // 1) x -> bf16
  cast_f32_bf16<<<(M_TOK * KF) / (256 * 8), 256, 0, stream>>>(x, Xb);
  // 2) W_eff -> bf16
  build_weff<<<dim3(KF / 64, NF / 64), 256, 0, stream>>>(weight, P, Lam, Q, mask, Wb);
  // 3) out = Xb @ Wb^T
  gemm_xwt<<<dim3(NF / BN, M_TOK / BM), 256, 0, stream>>>(Xb, Wb, out);
}